// Round 15
// baseline (3458.461 us; speedup 1.0000x reference)
//
#include <hip/hip_runtime.h>
#include <math.h>
#include <float.h>

constexpr int NE   = 64;      // experts
constexpr int ND   = 2048;    // hidden dim
constexpr int TOPK = 8;
constexpr int NWV  = 16;      // waves per block
constexpr int BLK  = NWV * 64;// 1024 threads
constexpr int EPW  = NE / NWV;// 4 experts per wave
constexpr int KC   = 64;      // k-chunk
constexpr int NCH  = ND / KC; // 32 chunks

// Numerics contract (DO NOT CHANGE — validated in rounds 11/14):
// h @ w.T emulating OpenBLAS sgemm fp32: K=2048 in kc panels
// {384,384,384,384,256,256} (chunk units: starts {0,6,12,18,24,28});
// per C-element per panel ONE accumulator, serial fp32 FMA with k strictly
// ascending; panel sums added to C in order (__fadd_rn). Then np ufuncs:
// l = fadd(fmul(raw, cs), cb), fp32, unfused. Rank on l32, ties -> lower
// index. Softmax value outputs fp32 (2% threshold).
__global__ __launch_bounds__(BLK)
void gate_kernel(const float* __restrict__ h, const float* __restrict__ w,
                 const float* __restrict__ cs, const float* __restrict__ cb,
                 float* __restrict__ out, int T)
{
    // smem layout (floats): [0..8191] w double-buffer (2 x 16KB chunks)
    //                       [8192..12287] sl logits (aliased epilogue zones below)
    __shared__ float smem[12288];   // 48 KB
    float* const wbuf = smem;               // [2][64e][64k] linear
    float* const sl   = smem + 8192;        // [e][t] logits
    float* const pp   = smem;               // epilogue alias: [t][e] swizzled probs
    float* const pinv = smem + 4096;        // epilogue alias: 64 floats

    const int tid  = threadIdx.x;
    const int lane = tid & 63;                       // lane = token
    const int wv   = __builtin_amdgcn_readfirstlane(tid >> 6);
    const int t0   = blockIdx.x * 64;
    const int e0   = wv * EPW;

    // staging role: thread stages 16B of w chunk; linear [e][k] layout
    const int se = tid >> 4;          // expert row 0..63
    const int sk = (tid & 15) * 4;    // k offset within chunk
    const float* wsrc = w + (size_t)se * ND + sk;
    const int sdst = tid * 4;         // = se*64 + sk  (float index)

    const float* hrow = h + (size_t)(t0 + lane) * ND;

    float C[EPW], a[EPW];
#pragma unroll
    for (int i = 0; i < EPW; ++i) C[i] = 0.f;

    // prologue: stage chunk 0 into buffer 0
    {
        const float4 v = *reinterpret_cast<const float4*>(wsrc);
        *reinterpret_cast<float4*>(&wbuf[sdst]) = v;
    }
    __syncthreads();

#pragma unroll 1
    for (int c = 0; c < NCH; ++c) {
        const int buf = c & 1;
        const bool pstart = (c == 0) || (c == 6) || (c == 12) || (c == 18) || (c == 24) || (c == 28);
        const bool pend   = (c == 5) || (c == 11) || (c == 17) || (c == 23) || (c == 27) || (c == 31);
        if (pstart) {
#pragma unroll
            for (int i = 0; i < EPW; ++i) a[i] = 0.f;
        }

        // prefetch next w chunk to ONE register float4 (low pressure)
        float4 nw;
        const bool hasn = (c + 1 < NCH);
        if (hasn) nw = *reinterpret_cast<const float4*>(wsrc + (c + 1) * KC);

        // ---- compute chunk c: serial FMA, k ascending (contract) ----
        const float* wbp = &wbuf[buf * 4096 + e0 * 64];
        const float* hp  = hrow + c * KC;
#pragma unroll
        for (int k4 = 0; k4 < KC / 4; ++k4) {
            const float4 h4 = *reinterpret_cast<const float4*>(hp + k4 * 4);
#pragma unroll
            for (int i = 0; i < EPW; ++i) {
                // same-address wave broadcast: conflict-free ds_read_b128
                const float4 w4 = *reinterpret_cast<const float4*>(wbp + i * 64 + k4 * 4);
                float t = a[i];
                t = __builtin_fmaf(h4.x, w4.x, t);
                t = __builtin_fmaf(h4.y, w4.y, t);
                t = __builtin_fmaf(h4.z, w4.z, t);
                t = __builtin_fmaf(h4.w, w4.w, t);
                a[i] = t;
            }
        }

        if (pend) {
#pragma unroll
            for (int i = 0; i < EPW; ++i) C[i] = __fadd_rn(C[i], a[i]);
        }

        __syncthreads();                 // compute done; safe to overwrite other buffer? (write below)
        if (hasn)
            *reinterpret_cast<float4*>(&wbuf[(buf ^ 1) * 4096 + sdst]) = nw;
        __syncthreads();                 // staged before next chunk's reads
    }

    // ---- epilogue (validated R11/R14) ----
#pragma unroll
    for (int i = 0; i < EPW; ++i) {
        const int e = e0 + i;
        // np ufuncs: mul then add, both rounded fp32, no fma contraction
        sl[e * 64 + lane] = __fadd_rn(__fmul_rn(C[i], cs[e]), cb[e]);
    }
    __syncthreads();

    float* const out_probs = out;                           // T*64
    float* const out_wts   = out + (size_t)T * NE;          // T*8
    float* const out_idx   = out + (size_t)T * (NE + TOPK); // T*8

    if (wv == 0) {
        float l[NE];
#pragma unroll
        for (int e = 0; e < NE; ++e) l[e] = sl[e * 64 + lane];

        float m = l[0];
#pragma unroll
        for (int e = 1; e < NE; ++e) m = fmaxf(m, l[e]);

        float u[NE];
        float s = 0.f;
#pragma unroll
        for (int e = 0; e < NE; ++e) {
            u[e] = expf(l[e] - m);
            s += u[e];
        }
        const float inv = 1.f / s;
        pinv[lane] = inv;

#pragma unroll
        for (int e = 0; e < NE; ++e)
            pp[lane * NE + (e ^ (lane & 31))] = u[e];

        // top-8 on l32; strict > insertion, e ascending => ties keep lower index
        float kv[TOPK]; int iv[TOPK];
#pragma unroll
        for (int j = 0; j < TOPK; ++j) { kv[j] = -FLT_MAX; iv[j] = 0; }
#pragma unroll
        for (int e = 0; e < NE; ++e) {
            float v = l[e]; int ix = e;
#pragma unroll
            for (int j = 0; j < TOPK; ++j) {
                const bool gt = v > kv[j];
                const float nv = gt ? kv[j] : v;
                const int   ni = gt ? iv[j] : ix;
                kv[j] = gt ? v  : kv[j];
                iv[j] = gt ? ix : iv[j];
                v = nv; ix = ni;
            }
        }

        float ws0[TOPK];
#pragma unroll
        for (int j = 0; j < TOPK; ++j)
            ws0[j] = pp[lane * NE + (iv[j] ^ (lane & 31))] * inv;

        const int tok = t0 + lane;
        *reinterpret_cast<float4*>(out_wts + (size_t)tok * TOPK)
            = make_float4(ws0[0], ws0[1], ws0[2], ws0[3]);
        *reinterpret_cast<float4*>(out_wts + (size_t)tok * TOPK + 4)
            = make_float4(ws0[4], ws0[5], ws0[6], ws0[7]);
        *reinterpret_cast<float4*>(out_idx + (size_t)tok * TOPK)
            = make_float4((float)iv[0], (float)iv[1], (float)iv[2], (float)iv[3]);
        *reinterpret_cast<float4*>(out_idx + (size_t)tok * TOPK + 4)
            = make_float4((float)iv[4], (float)iv[5], (float)iv[6], (float)iv[7]);
    }
    __syncthreads();

    // cooperative coalesced probs store: 4096 floats / 1024 threads = 4 each
    {
        const size_t base = (size_t)t0 * NE;
#pragma unroll
        for (int r = 0; r < (64 * NE) / BLK; ++r) {
            const int idx = r * BLK + tid;
            const int t = idx >> 6, e = idx & 63;
            out_probs[base + idx] = pp[t * NE + (e ^ (t & 31))] * pinv[t];
        }
    }
}

extern "C" void kernel_launch(void* const* d_in, const int* in_sizes, int n_in,
                              void* d_out, int out_size, void* d_ws, size_t ws_size,
                              hipStream_t stream)
{
    const float* h  = (const float*)d_in[0];
    const float* w  = (const float*)d_in[1];
    const float* cs = (const float*)d_in[2];
    const float* cb = (const float*)d_in[3];
    float* outp = (float*)d_out;
    const int T = in_sizes[0] / ND;   // 16384 tokens

    dim3 grid(T / 64);                // 256 blocks (1 per CU)
    dim3 block(BLK);                  // 1024 threads, 16 waves
    hipLaunchKernelGGL(gate_kernel, grid, block, 0, stream,
                       h, w, cs, cb, outp, T);
}

// Round 16
// 460.788 us; speedup vs baseline: 7.5055x; 7.5055x over previous
//
#include <hip/hip_runtime.h>
#include <math.h>
#include <float.h>

constexpr int NE   = 64;     // experts
constexpr int ND   = 2048;   // hidden dim
constexpr int TOPK = 8;
constexpr int TOKS = 64;     // tokens per block (= lanes)
constexpr int NWV  = 16;     // waves per block
constexpr int G    = NE / NWV; // 4 experts per wave

// Numerics contract (DO NOT CHANGE — validated in round 11, 237us pass):
// h @ w.T emulating OpenBLAS sgemm fp32: K=2048 in kc panels
// {384,384,384,384,256,256}; per C-element per panel ONE accumulator,
// serial fp32 FMA with k strictly ascending; panel sums added to C in
// order (__fadd_rn). Then np ufuncs: l = fadd(fmul(raw, cs), cb), fp32,
// unfused. Rank on l32, ties -> lower index. Softmax value outputs fp32.
__global__ __launch_bounds__(NWV * 64, 1)
void gate_kernel(const float* __restrict__ h, const float* __restrict__ w,
                 const float* __restrict__ cs, const float* __restrict__ cb,
                 float* __restrict__ out, int T)
{
    __shared__ float sl[NE * TOKS];   // l32 logits [e][t], 16 KB
    __shared__ float pp[TOKS * NE];   // [t][e] swizzled unnorm probs, 16 KB
    __shared__ float pinv[TOKS];

    const int tid  = threadIdx.x;
    const int lane = tid & 63;
    const int wv   = __builtin_amdgcn_readfirstlane(tid >> 6);
    const int tok  = blockIdx.x * TOKS + lane;
    const int e0   = wv * G;

    // Opaque zero in a VGPR: compiler cannot prove w addresses are
    // wave-uniform, so w loads go down the VECTOR memory path
    // (same-address global_load_dwordx4 -> single L1 access, broadcast,
    // vmcnt-pipelined) instead of s_load (out-of-order SMEM -> lgkmcnt(0)
    // full-drain stall per iteration, the R11 bottleneck).
    int lzero;
    asm volatile("v_mov_b32 %0, 0" : "=v"(lzero));

    const float* hrow = h + (size_t)tok * ND;
    // per-expert w row bases, each offset by the opaque lane zero
    const float* wr0 = w + (size_t)(e0 + 0) * ND + lzero;
    const float* wr1 = w + (size_t)(e0 + 1) * ND + lzero;
    const float* wr2 = w + (size_t)(e0 + 2) * ND + lzero;
    const float* wr3 = w + (size_t)(e0 + 3) * ND + lzero;

    float C[G];
#pragma unroll
    for (int g = 0; g < G; ++g) C[g] = 0.f;

    int k = 0;
#pragma unroll 1
    for (int p = 0; p < 6; ++p) {
        const int kend = (p < 4) ? (p + 1) * 384 : (1536 + (p - 3) * 256);

        float a[G];
#pragma unroll
        for (int g = 0; g < G; ++g) a[g] = 0.f;

#pragma unroll 1
        for (; k < kend; k += 8) {
            const float4 hv0 = *reinterpret_cast<const float4*>(hrow + k);
            const float4 hv1 = *reinterpret_cast<const float4*>(hrow + k + 4);

            const float4 wa0 = *reinterpret_cast<const float4*>(wr0 + k);
            const float4 wb0 = *reinterpret_cast<const float4*>(wr0 + k + 4);
            const float4 wa1 = *reinterpret_cast<const float4*>(wr1 + k);
            const float4 wb1 = *reinterpret_cast<const float4*>(wr1 + k + 4);
            const float4 wa2 = *reinterpret_cast<const float4*>(wr2 + k);
            const float4 wb2 = *reinterpret_cast<const float4*>(wr2 + k + 4);
            const float4 wa3 = *reinterpret_cast<const float4*>(wr3 + k);
            const float4 wb3 = *reinterpret_cast<const float4*>(wr3 + k + 4);

            // serial fp32 FMA, k strictly ascending (contract), per expert
            float t0 = a[0];
            t0 = __builtin_fmaf(hv0.x, wa0.x, t0);
            t0 = __builtin_fmaf(hv0.y, wa0.y, t0);
            t0 = __builtin_fmaf(hv0.z, wa0.z, t0);
            t0 = __builtin_fmaf(hv0.w, wa0.w, t0);
            t0 = __builtin_fmaf(hv1.x, wb0.x, t0);
            t0 = __builtin_fmaf(hv1.y, wb0.y, t0);
            t0 = __builtin_fmaf(hv1.z, wb0.z, t0);
            t0 = __builtin_fmaf(hv1.w, wb0.w, t0);
            a[0] = t0;

            float t1 = a[1];
            t1 = __builtin_fmaf(hv0.x, wa1.x, t1);
            t1 = __builtin_fmaf(hv0.y, wa1.y, t1);
            t1 = __builtin_fmaf(hv0.z, wa1.z, t1);
            t1 = __builtin_fmaf(hv0.w, wa1.w, t1);
            t1 = __builtin_fmaf(hv1.x, wb1.x, t1);
            t1 = __builtin_fmaf(hv1.y, wb1.y, t1);
            t1 = __builtin_fmaf(hv1.z, wb1.z, t1);
            t1 = __builtin_fmaf(hv1.w, wb1.w, t1);
            a[1] = t1;

            float t2 = a[2];
            t2 = __builtin_fmaf(hv0.x, wa2.x, t2);
            t2 = __builtin_fmaf(hv0.y, wa2.y, t2);
            t2 = __builtin_fmaf(hv0.z, wa2.z, t2);
            t2 = __builtin_fmaf(hv0.w, wa2.w, t2);
            t2 = __builtin_fmaf(hv1.x, wb2.x, t2);
            t2 = __builtin_fmaf(hv1.y, wb2.y, t2);
            t2 = __builtin_fmaf(hv1.z, wb2.z, t2);
            t2 = __builtin_fmaf(hv1.w, wb2.w, t2);
            a[2] = t2;

            float t3 = a[3];
            t3 = __builtin_fmaf(hv0.x, wa3.x, t3);
            t3 = __builtin_fmaf(hv0.y, wa3.y, t3);
            t3 = __builtin_fmaf(hv0.z, wa3.z, t3);
            t3 = __builtin_fmaf(hv0.w, wa3.w, t3);
            t3 = __builtin_fmaf(hv1.x, wb3.x, t3);
            t3 = __builtin_fmaf(hv1.y, wb3.y, t3);
            t3 = __builtin_fmaf(hv1.z, wb3.z, t3);
            t3 = __builtin_fmaf(hv1.w, wb3.w, t3);
            a[3] = t3;
        }

        // panel sums added to C in order (first panel: 0 + a, exact)
#pragma unroll
        for (int g = 0; g < G; ++g) C[g] = __fadd_rn(C[g], a[g]);
    }

    // np ufuncs: mul then add, both rounded fp32, no fma contraction
#pragma unroll
    for (int g = 0; g < G; ++g) {
        const int e = e0 + g;
        sl[e * TOKS + lane] = __fadd_rn(__fmul_rn(C[g], cs[e]), cb[e]);
    }
    __syncthreads();

    float* const out_probs = out;                           // T*64
    float* const out_wts   = out + (size_t)T * NE;          // T*8
    float* const out_idx   = out + (size_t)T * (NE + TOPK); // T*8

    if (wv == 0) {
        float l[NE];
#pragma unroll
        for (int e = 0; e < NE; ++e) l[e] = sl[e * TOKS + lane];

        float m = l[0];
#pragma unroll
        for (int e = 1; e < NE; ++e) m = fmaxf(m, l[e]);

        float u[NE];
        float s = 0.f;
#pragma unroll
        for (int e = 0; e < NE; ++e) {
            u[e] = expf(l[e] - m);
            s += u[e];
        }
        const float inv = 1.f / s;
        pinv[lane] = inv;

        // stage unnormalized probs, XOR-swizzled (conflict-free)
#pragma unroll
        for (int e = 0; e < NE; ++e)
            pp[lane * NE + (e ^ (lane & 31))] = u[e];

        // top-8 on l32; strict > insertion, e ascending => ties keep lower index
        float kv[TOPK]; int iv[TOPK];
#pragma unroll
        for (int j = 0; j < TOPK; ++j) { kv[j] = -FLT_MAX; iv[j] = 0; }
#pragma unroll
        for (int e = 0; e < NE; ++e) {
            float v = l[e]; int ix = e;
#pragma unroll
            for (int j = 0; j < TOPK; ++j) {
                const bool gt = v > kv[j];
                const float nv = gt ? kv[j] : v;
                const int   ni = gt ? iv[j] : ix;
                kv[j] = gt ? v  : kv[j];
                iv[j] = gt ? ix : iv[j];
                v = nv; ix = ni;
            }
        }

        float ws0[TOPK];
#pragma unroll
        for (int j = 0; j < TOPK; ++j)
            ws0[j] = pp[lane * NE + (iv[j] ^ (lane & 31))] * inv;

        *reinterpret_cast<float4*>(out_wts + (size_t)tok * TOPK)
            = make_float4(ws0[0], ws0[1], ws0[2], ws0[3]);
        *reinterpret_cast<float4*>(out_wts + (size_t)tok * TOPK + 4)
            = make_float4(ws0[4], ws0[5], ws0[6], ws0[7]);
        *reinterpret_cast<float4*>(out_idx + (size_t)tok * TOPK)
            = make_float4((float)iv[0], (float)iv[1], (float)iv[2], (float)iv[3]);
        *reinterpret_cast<float4*>(out_idx + (size_t)tok * TOPK + 4)
            = make_float4((float)iv[4], (float)iv[5], (float)iv[6], (float)iv[7]);
    }
    __syncthreads();

    // cooperative coalesced probs store: 4096 floats / 1024 threads = 4 each
    {
        const size_t base = (size_t)blockIdx.x * TOKS * NE;
#pragma unroll
        for (int r = 0; r < (TOKS * NE) / (NWV * 64); ++r) {
            const int idx = r * (NWV * 64) + tid;
            const int t = idx >> 6, e = idx & 63;
            out_probs[base + idx] = pp[t * NE + (e ^ (t & 31))] * pinv[t];
        }
    }
}

extern "C" void kernel_launch(void* const* d_in, const int* in_sizes, int n_in,
                              void* d_out, int out_size, void* d_ws, size_t ws_size,
                              hipStream_t stream)
{
    const float* h  = (const float*)d_in[0];
    const float* w  = (const float*)d_in[1];
    const float* cs = (const float*)d_in[2];
    const float* cb = (const float*)d_in[3];
    float* outp = (float*)d_out;
    const int T = in_sizes[0] / ND;   // 16384 tokens

    dim3 grid(T / TOKS);              // 256 blocks
    dim3 block(NWV * 64);             // 1024 threads, 16 waves
    hipLaunchKernelGGL(gate_kernel, grid, block, 0, stream,
                       h, w, cs, cb, outp, T);
}